// Round 2
// baseline (2479.017 us; speedup 1.0000x reference)
//
#include <hip/hip_runtime.h>

#define NN 100000
#define NE 1600000
#define DIM 128
#define EDIM 16
#define NL 3

typedef unsigned short u16;
typedef unsigned int u32;

__device__ __forceinline__ float b2f(u16 u){ u32 x = ((u32)u)<<16; float f; __builtin_memcpy(&f,&x,4); return f; }
__device__ __forceinline__ u16 f2b(float f){ u32 x; __builtin_memcpy(&x,&f,4); u32 r = (x + 0x7fffu + ((x>>16)&1u))>>16; return (u16)r; }

// ---------------- dtype probes ----------------
// float tensors: bf16 vs f32. bf16 data -> ~100% of u16 words have sane exponent;
// f32 data -> low-order halves are random mantissa bits, only ~58% sane.
__global__ void k_probe_f(const u16* __restrict__ x, int* fflag){
  __shared__ int cnt;
  if (threadIdx.x==0) cnt = 0;
  __syncthreads();
  int sane = 0;
  for (int j=threadIdx.x; j<2048; j+=256){
    u16 w = x[j];
    int e = (w>>7)&0xFF;
    if (w==0 || (e>=100 && e<=140)) sane++;
  }
  atomicAdd(&cnt, sane);
  __syncthreads();
  if (threadIdx.x==0) *fflag = (cnt < 1900) ? 1 : 0;   // 1 => float32
}

// edge_index int64 vs int32: int64 positives have all-zero high words
__global__ void k_probe_i(const int* __restrict__ ei, int* iflag){
  int j = blockIdx.x*256 + threadIdx.x;
  if (j < 1024){ if (ei[2*j+1] != 0) atomicOr(iflag, 1); }  // !=0 => int32
}

// ---------------- utility ----------------
__global__ void k_zero32(int* p, int n){ int i = blockIdx.x*256 + threadIdx.x; if (i<n) p[i]=0; }
__global__ void k_zerof(float* p, int n){ int i = blockIdx.x*256 + threadIdx.x; if (i<n) p[i]=0.f; }

__global__ void k_x2f(const void* __restrict__ x, float* __restrict__ h, const int* __restrict__ fflag){
  int i = blockIdx.x*256 + threadIdx.x;
  if (i >= NN*DIM) return;
  h[i] = (*fflag) ? ((const float*)x)[i] : b2f(((const u16*)x)[i]);
}

// convert all small params into canonical bf16 copies (segmented)
#define SEG_WL    0
#define SEG_WR    49152
#define SEG_WE    98304
#define SEG_ATT   104448
#define SEG_GAM   104832
#define SEG_BET   105216
#define SEG_WF    105600
#define SEG_BF    121984
#define SEG_BL    122112
#define SEG_BR    122496
#define SEG_TOTAL 122880

__global__ void k_cvt_params(const void* Wl, const void* Wr, const void* We, const void* att,
                             const void* gam, const void* bet, const void* Wf, const void* bf,
                             const void* bl, const void* br,
                             u16* __restrict__ dst, const int* __restrict__ fflag){
  int i = blockIdx.x*256 + threadIdx.x;
  if (i >= SEG_TOTAL) return;
  const void* src; int off;
  if      (i < SEG_WR)  { src = Wl;  off = i - SEG_WL; }
  else if (i < SEG_WE)  { src = Wr;  off = i - SEG_WR; }
  else if (i < SEG_ATT) { src = We;  off = i - SEG_WE; }
  else if (i < SEG_GAM) { src = att; off = i - SEG_ATT; }
  else if (i < SEG_BET) { src = gam; off = i - SEG_GAM; }
  else if (i < SEG_WF)  { src = bet; off = i - SEG_BET; }
  else if (i < SEG_BF)  { src = Wf;  off = i - SEG_WF; }
  else if (i < SEG_BL)  { src = bf;  off = i - SEG_BF; }
  else if (i < SEG_BR)  { src = bl;  off = i - SEG_BL; }
  else                  { src = br;  off = i - SEG_BR; }
  dst[i] = (*fflag) ? f2b(((const float*)src)[off]) : ((const u16*)src)[off];
}

// ---------------- CSR build ----------------
__global__ void k_count(const int* __restrict__ ei, const int* __restrict__ iflag, int* __restrict__ counts){
  int e = blockIdx.x*256 + threadIdx.x; if (e >= NE) return;
  int d;
  if (*iflag) d = ei[NE + e];
  else        d = (int)((const long long*)ei)[NE + e];
  atomicAdd(&counts[d], 1);
}

__global__ void k_scanA(const int* __restrict__ counts, int* __restrict__ offs, int* __restrict__ bsums){
  __shared__ int s[1024];
  int t = threadIdx.x; int i = blockIdx.x*1024 + t;
  int v = (i < NN) ? counts[i] : 0;
  s[t] = v; __syncthreads();
  for (int off=1; off<1024; off<<=1){
    int x = (t>=off) ? s[t-off] : 0;
    __syncthreads();
    s[t] += x;
    __syncthreads();
  }
  if (i < NN) offs[i] = s[t] - v;
  if (t == 1023) bsums[blockIdx.x] = s[1023];
}
__global__ void k_scanB(int* bsums, int* offs, int nb){
  if (threadIdx.x==0 && blockIdx.x==0){
    int run = 0;
    for (int j=0;j<nb;j++){ int tmp=bsums[j]; bsums[j]=run; run+=tmp; }
    offs[NN] = run;
  }
}
__global__ void k_scanC(int* __restrict__ offs, const int* __restrict__ bsums){
  int i = blockIdx.x*256 + threadIdx.x;
  if (i < NN) offs[i] += bsums[i>>10];
}

__global__ void k_fill(const int* __restrict__ ei, const int* __restrict__ iflag,
                       const int* __restrict__ offs, int* __restrict__ counts,
                       int* __restrict__ srcs, int* __restrict__ eids){
  int e = blockIdx.x*256 + threadIdx.x; if (e >= NE) return;
  int s, d;
  if (*iflag){ s = ei[e]; d = ei[NE + e]; }
  else { const long long* e64 = (const long long*)ei; s = (int)e64[e]; d = (int)e64[NE + e]; }
  int pos = offs[d] + atomicAdd(&counts[d], 1);
  srcs[pos] = s; eids[pos] = e;
}

// ---------------- node GEMM: out[n][c] = sum_k in[n][k]*W[k][c] + b[c] ----------------
// W,b are canonical bf16. store_f32: if set AND *fflag, store fp32 output (final proj).
__global__ __launch_bounds__(256) void k_gemm(const float* __restrict__ in,
    const u16* __restrict__ W0, const u16* __restrict__ b0, void* __restrict__ out0,
    const u16* __restrict__ W1, const u16* __restrict__ b1, void* __restrict__ out1,
    int store_f32, const int* __restrict__ fflag)
{
  __shared__ __align__(16) u16 Ws[DIM*DIM];
  __shared__ __align__(16) u16 Xs[64*DIM];
  const u16* W  = blockIdx.y ? W1 : W0;
  const u16* bi = blockIdx.y ? b1 : b0;
  void* out     = blockIdx.y ? out1 : out0;
  int t = threadIdx.x;
  for (int j=t; j<DIM*DIM; j+=256) Ws[j] = W[j];
  int n0 = blockIdx.x*64;
  for (int j=t; j<64*DIM; j+=256){
    int r = j>>7, c = j&127; int n = n0 + r;
    Xs[j] = (n < NN) ? f2b(in[(size_t)n*DIM + c]) : (u16)0;
  }
  __syncthreads();
  int cg = t & 15, c0 = cg*8;
  int ng = t >> 4, r0 = ng*4;
  float acc[4][8];
  #pragma unroll
  for (int j=0;j<4;j++)
    #pragma unroll
    for (int i=0;i<8;i++) acc[j][i] = 0.f;
  for (int k=0;k<DIM;k++){
    uint4 wv = *(const uint4*)&Ws[k*DIM + c0];
    float w[8];
    w[0]=b2f((u16)(wv.x&0xffff)); w[1]=b2f((u16)(wv.x>>16));
    w[2]=b2f((u16)(wv.y&0xffff)); w[3]=b2f((u16)(wv.y>>16));
    w[4]=b2f((u16)(wv.z&0xffff)); w[5]=b2f((u16)(wv.z>>16));
    w[6]=b2f((u16)(wv.w&0xffff)); w[7]=b2f((u16)(wv.w>>16));
    float xv[4];
    #pragma unroll
    for (int j=0;j<4;j++) xv[j] = b2f(Xs[(r0+j)*DIM + k]);
    #pragma unroll
    for (int j=0;j<4;j++)
      #pragma unroll
      for (int i=0;i<8;i++) acc[j][i] += xv[j]*w[i];
  }
  float bv[8];
  #pragma unroll
  for (int i=0;i<8;i++) bv[i] = b2f(bi[c0+i]);
  bool f32out = store_f32 && (*fflag);
  #pragma unroll
  for (int j=0;j<4;j++){
    int n = n0 + r0 + j;
    if (n < NN){
      float r[8];
      #pragma unroll
      for (int i=0;i<8;i++) r[i] = acc[j][i] + bv[i];
      if (f32out){
        float* op = (float*)out + (size_t)n*DIM + c0;
        *(float4*)op       = make_float4(r[0],r[1],r[2],r[3]);
        *(float4*)(op + 4) = make_float4(r[4],r[5],r[6],r[7]);
      } else {
        u32 pk[4];
        #pragma unroll
        for (int i=0;i<4;i++)
          pk[i] = (u32)f2b(r[2*i]) | ((u32)f2b(r[2*i+1])<<16);
        *(uint4*)&((u16*)out)[(size_t)n*DIM + c0] = make_uint4(pk[0],pk[1],pk[2],pk[3]);
      }
    }
  }
}

// ---------------- attention + aggregation: one wave per node, online softmax ----------------
__global__ __launch_bounds__(256) void k_attn(const int* __restrict__ offs, const int* __restrict__ srcs,
    const int* __restrict__ eids, const void* __restrict__ eattr,
    const u16* __restrict__ We, const u16* __restrict__ att,
    const u16* __restrict__ gl, const u16* __restrict__ gr, float* __restrict__ agg,
    const int* __restrict__ fflag)
{
  __shared__ float sWe[EDIM*DIM];
  __shared__ float sAtt[DIM];
  int t = threadIdx.x;
  for (int j=t; j<EDIM*DIM; j+=256) sWe[j] = b2f(We[j]);
  if (t < DIM) sAtt[t] = b2f(att[t]);
  __syncthreads();
  int lane = t & 63;
  int node = blockIdx.x*4 + (t>>6);
  float we0[EDIM], we1[EDIM];
  #pragma unroll
  for (int k=0;k<EDIM;k++){ we0[k]=sWe[k*DIM + 2*lane]; we1[k]=sWe[k*DIM + 2*lane + 1]; }
  float att0 = sAtt[2*lane], att1 = sAtt[2*lane+1];
  if (node >= NN) return;
  bool isf = (*fflag) != 0;
  u32 g = ((const u32*)gr)[node*64 + lane];
  float gr0 = b2f((u16)(g&0xffff)), gr1 = b2f((u16)(g>>16));
  float m = -INFINITY, dd = 0.f, O0 = 0.f, O1 = 0.f;
  int beg = offs[node], end = offs[node+1];
  for (int e=beg; e<end; ++e){
    int s = srcs[e]; int eid = eids[e];
    u32 gx = ((const u32*)gl)[s*64 + lane];
    float xj0 = b2f((u16)(gx&0xffff)), xj1 = b2f((u16)(gx>>16));
    float e0 = xj0 + gr0, e1 = xj1 + gr1;
    float a[EDIM];
    if (isf){
      const float4* ea = (const float4*)((const float*)eattr + (size_t)eid*EDIM);
      float4 p0 = ea[0], p1 = ea[1], p2 = ea[2], p3 = ea[3];
      a[0]=p0.x; a[1]=p0.y; a[2]=p0.z; a[3]=p0.w;
      a[4]=p1.x; a[5]=p1.y; a[6]=p1.z; a[7]=p1.w;
      a[8]=p2.x; a[9]=p2.y; a[10]=p2.z; a[11]=p2.w;
      a[12]=p3.x; a[13]=p3.y; a[14]=p3.z; a[15]=p3.w;
    } else {
      const uint4* ea4 = (const uint4*)((const u16*)eattr + (size_t)eid*EDIM);
      uint4 u0v = ea4[0], u1v = ea4[1];
      u32 eu[8] = {u0v.x,u0v.y,u0v.z,u0v.w,u1v.x,u1v.y,u1v.z,u1v.w};
      #pragma unroll
      for (int q=0;q<8;q++){
        a[2*q]   = b2f((u16)(eu[q]&0xffff));
        a[2*q+1] = b2f((u16)(eu[q]>>16));
      }
    }
    #pragma unroll
    for (int k=0;k<EDIM;k++){ e0 += a[k]*we0[k]; e1 += a[k]*we1[k]; }
    e0 = e0 > 0.f ? e0 : 0.2f*e0;   // GATv2 leaky_relu 0.2
    e1 = e1 > 0.f ? e1 : 0.2f*e1;
    float part = e0*att0 + e1*att1;
    part += __shfl_xor(part, 1);
    part += __shfl_xor(part, 2);
    part += __shfl_xor(part, 4);
    part += __shfl_xor(part, 8);    // head logit over 16-lane head group
    float nm = fmaxf(m, part);
    float sc = __expf(m - nm);
    float pp = __expf(part - nm);
    dd = dd*sc + pp;
    O0 = O0*sc + pp*xj0;
    O1 = O1*sc + pp*xj1;
    m = nm;
  }
  float inv = 1.f/(dd + 1e-16f);
  ((float2*)agg)[node*64 + lane] = make_float2(O0*inv, O1*inv);
}

// ---------------- batch norm ----------------
__global__ __launch_bounds__(256) void k_bnstats(const float* __restrict__ agg, float* __restrict__ stats){
  int t = threadIdx.x;
  int p = t & 63;
  int rg = t >> 6;
  float s0=0,s1=0,q0=0,q1=0;
  for (int r = blockIdx.x*4 + rg; r < NN; r += 256*4){
    float2 v = ((const float2*)agg)[(size_t)r*64 + p];
    s0 += v.x; s1 += v.y; q0 += v.x*v.x; q1 += v.y*v.y;
  }
  int c0 = 2*p;
  atomicAdd(&stats[c0],     s0); atomicAdd(&stats[c0+1],     s1);
  atomicAdd(&stats[DIM+c0], q0); atomicAdd(&stats[DIM+c0+1], q1);
}

__global__ __launch_bounds__(256) void k_bnapply(const float* __restrict__ agg, const float* __restrict__ stats,
    const u16* __restrict__ gamma, const u16* __restrict__ beta, float* __restrict__ h){
  int i = blockIdx.x*256 + threadIdx.x;
  if (i >= NN*64) return;
  int p = i & 63; int c0 = 2*p;
  float2 v = ((const float2*)agg)[i];
  const float invN = 1.f/(float)NN;
  float mu0 = stats[c0]*invN,   mu1 = stats[c0+1]*invN;
  float va0 = stats[DIM+c0]*invN   - mu0*mu0;
  float va1 = stats[DIM+c0+1]*invN - mu1*mu1;
  float rs0 = rsqrtf(fmaxf(va0, 0.f) + 1e-5f), rs1 = rsqrtf(fmaxf(va1, 0.f) + 1e-5f);
  float y0 = (v.x - mu0)*rs0*b2f(gamma[c0])   + b2f(beta[c0]);
  float y1 = (v.y - mu1)*rs1*b2f(gamma[c0+1]) + b2f(beta[c0+1]);
  y0 = y0 > 0.f ? y0 : 0.02f*y0;
  y1 = y1 > 0.f ? y1 : 0.02f*y1;
  ((float2*)h)[i] = make_float2(y0, y1);
}

// ---------------- launch ----------------
extern "C" void kernel_launch(void* const* d_in, const int* in_sizes, int n_in,
                              void* d_out, int out_size, void* d_ws, size_t ws_size,
                              hipStream_t stream){
  (void)in_sizes; (void)n_in; (void)out_size; (void)ws_size;
  const void* x    = d_in[0];
  const int* ei    = (const int*)d_in[1];
  const void* eattr= d_in[2];
  // d_in[9] = conv bias: cancels under BN mean-subtraction, skipped
  char* p = (char*)d_ws;
  auto alloc = [&](size_t b)->void*{ void* q = p; p += (b + 255) & ~(size_t)255; return q; };
  float* h      = (float*)alloc((size_t)NN*DIM*4);
  float* agg    = (float*)alloc((size_t)NN*DIM*4);
  u16*   gl     = (u16*)  alloc((size_t)NN*DIM*2);
  u16*   gr     = (u16*)  alloc((size_t)NN*DIM*2);
  int*   offs   = (int*)  alloc((size_t)(NN+1)*4);
  int*   counts = (int*)  alloc((size_t)NN*4);
  int*   srcs   = (int*)  alloc((size_t)NE*4);
  int*   eids   = (int*)  alloc((size_t)NE*4);
  float* stats  = (float*)alloc(256*4);
  int*   bsums  = (int*)  alloc(128*4);
  int*   flags  = (int*)  alloc(8);           // [0]=fflag (f32?), [1]=iflag (int32?)
  u16*   cpar   = (u16*)  alloc((size_t)SEG_TOTAL*2);

  int* fflag = flags;
  int* iflag = flags + 1;

  k_zero32<<<1,256,0,stream>>>(flags, 2);
  k_probe_f<<<1,256,0,stream>>>((const u16*)x, fflag);
  k_probe_i<<<4,256,0,stream>>>(ei, iflag);
  k_cvt_params<<<(SEG_TOTAL+255)/256,256,0,stream>>>(d_in[3], d_in[5], d_in[7], d_in[8],
      d_in[10], d_in[11], d_in[12], d_in[13], d_in[4], d_in[6], cpar, fflag);
  const u16* cWl = cpar + SEG_WL;  const u16* cWr = cpar + SEG_WR;
  const u16* cWe = cpar + SEG_WE;  const u16* cAtt= cpar + SEG_ATT;
  const u16* cGam= cpar + SEG_GAM; const u16* cBet= cpar + SEG_BET;
  const u16* cWf = cpar + SEG_WF;  const u16* cBf = cpar + SEG_BF;
  const u16* cBl = cpar + SEG_BL;  const u16* cBr = cpar + SEG_BR;

  k_x2f<<<(NN*DIM+255)/256,256,0,stream>>>(x, h, fflag);
  k_zero32<<<(NN+255)/256,256,0,stream>>>(counts, NN);
  k_count<<<(NE+255)/256,256,0,stream>>>(ei, iflag, counts);
  const int nbA = (NN+1023)/1024;
  k_scanA<<<nbA,1024,0,stream>>>(counts, offs, bsums);
  k_scanB<<<1,1,0,stream>>>(bsums, offs, nbA);
  k_scanC<<<(NN+255)/256,256,0,stream>>>(offs, bsums);
  k_zero32<<<(NN+255)/256,256,0,stream>>>(counts, NN);
  k_fill<<<(NE+255)/256,256,0,stream>>>(ei, iflag, offs, counts, srcs, eids);

  for (int L=0; L<NL; ++L){
    k_gemm<<<dim3((NN+63)/64,2),256,0,stream>>>(h,
        cWl + (size_t)L*DIM*DIM, cBl + L*DIM, gl,
        cWr + (size_t)L*DIM*DIM, cBr + L*DIM, gr, 0, fflag);
    k_zerof<<<1,256,0,stream>>>(stats, 256);
    k_attn<<<(NN+3)/4,256,0,stream>>>(offs, srcs, eids, eattr,
        cWe + (size_t)L*EDIM*DIM, cAtt + L*DIM, gl, gr, agg, fflag);
    k_bnstats<<<256,256,0,stream>>>(agg, stats);
    k_bnapply<<<(NN*64+255)/256,256,0,stream>>>(agg, stats, cGam + L*DIM, cBet + L*DIM, h);
  }
  k_gemm<<<dim3((NN+63)/64,1),256,0,stream>>>(h, cWf, cBf, d_out, cWf, cBf, d_out, 1, fflag);
}

// Round 3
// 1777.885 us; speedup vs baseline: 1.3944x; 1.3944x over previous
//
#include <hip/hip_runtime.h>

#define NN 100000
#define NE 1600000
#define DIM 128
#define EDIM 16
#define NL 3

typedef unsigned short u16;
typedef unsigned int u32;
typedef __attribute__((ext_vector_type(8))) short bf16x8;
typedef __attribute__((ext_vector_type(4))) float f32x4;

__device__ __forceinline__ float b2f(u16 u){ u32 x = ((u32)u)<<16; float f; __builtin_memcpy(&f,&x,4); return f; }
__device__ __forceinline__ float b2f_lo(u32 u){ u32 x = u<<16; float f; __builtin_memcpy(&f,&x,4); return f; }
__device__ __forceinline__ float b2f_hi(u32 u){ u32 x = u & 0xffff0000u; float f; __builtin_memcpy(&f,&x,4); return f; }
__device__ __forceinline__ u16 f2b(float f){ u32 x; __builtin_memcpy(&x,&f,4); u32 r = (x + 0x7fffu + ((x>>16)&1u))>>16; return (u16)r; }

// ---------------- dtype probes ----------------
__global__ void k_probe_f(const u16* __restrict__ x, int* fflag){
  __shared__ int cnt;
  if (threadIdx.x==0) cnt = 0;
  __syncthreads();
  int sane = 0;
  for (int j=threadIdx.x; j<2048; j+=256){
    u16 w = x[j];
    int e = (w>>7)&0xFF;
    if (w==0 || (e>=100 && e<=140)) sane++;
  }
  atomicAdd(&cnt, sane);
  __syncthreads();
  if (threadIdx.x==0) *fflag = (cnt < 1900) ? 1 : 0;   // 1 => float32
}
__global__ void k_probe_i(const int* __restrict__ ei, int* iflag){
  int j = blockIdx.x*256 + threadIdx.x;
  if (j < 1024){ if (ei[2*j+1] != 0) atomicOr(iflag, 1); }  // !=0 => int32
}

// ---------------- utility ----------------
__global__ void k_zero32(int* p, int n){ int i = blockIdx.x*256 + threadIdx.x; if (i<n) p[i]=0; }
__global__ void k_zerof(float* p, int n){ int i = blockIdx.x*256 + threadIdx.x; if (i<n) p[i]=0.f; }

__global__ void k_x2f(const void* __restrict__ x, float* __restrict__ h, const int* __restrict__ fflag){
  int i = blockIdx.x*256 + threadIdx.x;
  if (i >= NN*DIM/4) return;
  float4 v;
  if (*fflag) v = ((const float4*)x)[i];
  else {
    uint2 u = ((const uint2*)x)[i];
    v = make_float4(b2f_lo(u.x), b2f_hi(u.x), b2f_lo(u.y), b2f_hi(u.y));
  }
  ((float4*)h)[i] = v;
}

// canonical bf16 params; Wl/Wr/Wf stored TRANSPOSED (dst[c][k] = src[k][c])
#define SEG_WL    0
#define SEG_WR    49152
#define SEG_WE    98304
#define SEG_ATT   104448
#define SEG_GAM   104832
#define SEG_BET   105216
#define SEG_WF    105600
#define SEG_BF    121984
#define SEG_BL    122112
#define SEG_BR    122496
#define SEG_TOTAL 122880

__global__ void k_cvt_params(const void* Wl, const void* Wr, const void* We, const void* att,
                             const void* gam, const void* bet, const void* Wf, const void* bf,
                             const void* bl, const void* br,
                             u16* __restrict__ dst, const int* __restrict__ fflag){
  int i = blockIdx.x*256 + threadIdx.x;
  if (i >= SEG_TOTAL) return;
  const void* src; int off;
  if (i < SEG_WR){                       // Wl^T
    int o = i - SEG_WL; int l = o>>14, r = o&16383, c = r>>7, k = r&127;
    src = Wl; off = (l<<14)|(k<<7)|c;
  } else if (i < SEG_WE){                // Wr^T
    int o = i - SEG_WR; int l = o>>14, r = o&16383, c = r>>7, k = r&127;
    src = Wr; off = (l<<14)|(k<<7)|c;
  } else if (i < SEG_ATT){ src = We;  off = i - SEG_WE; }
  else if (i < SEG_GAM)  { src = att; off = i - SEG_ATT; }
  else if (i < SEG_BET)  { src = gam; off = i - SEG_GAM; }
  else if (i < SEG_WF)   { src = bet; off = i - SEG_BET; }
  else if (i < SEG_BF){                  // Wf^T
    int o = i - SEG_WF; int c = o>>7, k = o&127;
    src = Wf; off = (k<<7)|c;
  }
  else if (i < SEG_BL)   { src = bf;  off = i - SEG_BF; }
  else if (i < SEG_BR)   { src = bl;  off = i - SEG_BL; }
  else                   { src = br;  off = i - SEG_BR; }
  dst[i] = (*fflag) ? f2b(((const float*)src)[off]) : ((const u16*)src)[off];
}

// ---------------- CSR build ----------------
__global__ void k_count(const int* __restrict__ ei, const int* __restrict__ iflag, int* __restrict__ counts){
  int e = blockIdx.x*256 + threadIdx.x; if (e >= NE) return;
  int d;
  if (*iflag) d = ei[NE + e];
  else        d = (int)((const long long*)ei)[NE + e];
  atomicAdd(&counts[d], 1);
}
__global__ void k_scanA(const int* __restrict__ counts, int* __restrict__ offs, int* __restrict__ bsums){
  __shared__ int s[1024];
  int t = threadIdx.x; int i = blockIdx.x*1024 + t;
  int v = (i < NN) ? counts[i] : 0;
  s[t] = v; __syncthreads();
  for (int off=1; off<1024; off<<=1){
    int x = (t>=off) ? s[t-off] : 0;
    __syncthreads();
    s[t] += x;
    __syncthreads();
  }
  if (i < NN) offs[i] = s[t] - v;
  if (t == 1023) bsums[blockIdx.x] = s[1023];
}
__global__ void k_scanB(int* bsums, int* offs, int nb){
  if (threadIdx.x==0 && blockIdx.x==0){
    int run = 0;
    for (int j=0;j<nb;j++){ int tmp=bsums[j]; bsums[j]=run; run+=tmp; }
    offs[NN] = run;
  }
}
__global__ void k_scanC(int* __restrict__ offs, const int* __restrict__ bsums){
  int i = blockIdx.x*256 + threadIdx.x;
  if (i < NN) offs[i] += bsums[i>>10];
}

// fill CSR: srcs + edge_attr permuted into CSR order as bf16 (eperm)
__global__ void k_fill(const int* __restrict__ ei, const int* __restrict__ iflag,
                       const int* __restrict__ offs, int* __restrict__ counts,
                       int* __restrict__ srcs, u16* __restrict__ eperm,
                       const void* __restrict__ eattr, const int* __restrict__ fflag){
  int e = blockIdx.x*256 + threadIdx.x; if (e >= NE) return;
  int s, d;
  if (*iflag){ s = ei[e]; d = ei[NE + e]; }
  else { const long long* e64 = (const long long*)ei; s = (int)e64[e]; d = (int)e64[NE + e]; }
  int pos = offs[d] + atomicAdd(&counts[d], 1);
  srcs[pos] = s;
  uint4 lo, hi;
  if (*fflag){
    const float4* s4 = (const float4*)((const float*)eattr + (size_t)e*EDIM);
    float4 a = s4[0], b = s4[1], c = s4[2], dd = s4[3];
    lo.x = (u32)f2b(a.x) | ((u32)f2b(a.y)<<16); lo.y = (u32)f2b(a.z) | ((u32)f2b(a.w)<<16);
    lo.z = (u32)f2b(b.x) | ((u32)f2b(b.y)<<16); lo.w = (u32)f2b(b.z) | ((u32)f2b(b.w)<<16);
    hi.x = (u32)f2b(c.x) | ((u32)f2b(c.y)<<16); hi.y = (u32)f2b(c.z) | ((u32)f2b(c.w)<<16);
    hi.z = (u32)f2b(dd.x)| ((u32)f2b(dd.y)<<16);hi.w = (u32)f2b(dd.z)| ((u32)f2b(dd.w)<<16);
  } else {
    const uint4* s4 = (const uint4*)((const u16*)eattr + (size_t)e*EDIM);
    lo = s4[0]; hi = s4[1];
  }
  uint4* dst = (uint4*)(eperm + (size_t)pos*EDIM);
  dst[0] = lo; dst[1] = hi;
}

// ---------------- MFMA node GEMM: out[n][c] = sum_k in[n][k]*W[k][c] + b[c] ----------------
// WT = transposed weight [c][k] bf16. 64 rows x 128 cols per block, 4 waves.
#define LSTR 136   // padded LDS row stride (bf16 elems): +16B breaks bank conflicts
__global__ __launch_bounds__(256) void k_gemm(const float* __restrict__ in,
    const u16* __restrict__ WT0, const u16* __restrict__ b0, void* __restrict__ out0,
    const u16* __restrict__ WT1, const u16* __restrict__ b1, void* __restrict__ out1,
    int store_f32, const int* __restrict__ fflag)
{
  __shared__ __align__(16) u16 Xs[64*LSTR];
  __shared__ __align__(16) u16 Ws[128*LSTR];
  const u16* WT = blockIdx.y ? WT1 : WT0;
  const u16* bi = blockIdx.y ? b1 : b0;
  void* out     = blockIdx.y ? out1 : out0;
  int t = threadIdx.x;
  int n0 = blockIdx.x*64;
  // stage W^T (128x128 bf16 = 2048 uint4), coalesced
  const uint4* w4 = (const uint4*)WT;
  for (int p = t; p < 2048; p += 256){
    int c = p >> 4, k16 = p & 15;
    *(uint4*)&Ws[c*LSTR + k16*8] = w4[p];
  }
  // stage X (64x128 f32 -> bf16)
  for (int p = t; p < 2048; p += 256){
    int r = p >> 5, c4 = p & 31;
    int n = n0 + r;
    uint2 pk;
    if (n < NN){
      float4 v = *(const float4*)(in + (size_t)n*DIM + c4*4);
      pk.x = (u32)f2b(v.x) | ((u32)f2b(v.y)<<16);
      pk.y = (u32)f2b(v.z) | ((u32)f2b(v.w)<<16);
    } else pk = make_uint2(0,0);
    *(uint2*)&Xs[r*LSTR + c4*4] = pk;
  }
  __syncthreads();
  int lane = t & 63, wv = t >> 6;
  int m = lane & 15, q = lane >> 4;
  f32x4 acc[8];
  #pragma unroll
  for (int i=0;i<8;i++) acc[i] = (f32x4){0.f,0.f,0.f,0.f};
  #pragma unroll
  for (int ks=0; ks<4; ks++){
    bf16x8 af = *(const bf16x8*)&Xs[(wv*16 + m)*LSTR + ks*32 + q*8];
    #pragma unroll
    for (int nt=0; nt<8; nt++){
      bf16x8 bfr = *(const bf16x8*)&Ws[(nt*16 + m)*LSTR + ks*32 + q*8];
      acc[nt] = __builtin_amdgcn_mfma_f32_16x16x32_bf16(af, bfr, acc[nt], 0, 0, 0);
    }
  }
  bool f32out = store_f32 && (*fflag);
  #pragma unroll
  for (int nt=0; nt<8; nt++){
    int col = nt*16 + m;
    float bvv = b2f(bi[col]);
    #pragma unroll
    for (int r=0;r<4;r++){
      int row = n0 + wv*16 + q*4 + r;
      if (row < NN){
        float val = acc[nt][r] + bvv;
        if (f32out) ((float*)out)[(size_t)row*DIM + col] = val;
        else        ((u16*)out)[(size_t)row*DIM + col] = f2b(val);
      }
    }
  }
}

// ---------------- attention: one wave per node, online softmax, 4-way unrolled ----------------
__global__ __launch_bounds__(256) void k_attn(const int* __restrict__ offs, const int* __restrict__ srcs,
    const u16* __restrict__ eperm, const u16* __restrict__ We, const u16* __restrict__ att,
    const u16* __restrict__ gl, const u16* __restrict__ gr, float* __restrict__ agg)
{
  __shared__ float sWe[EDIM*DIM];
  __shared__ float sAtt[DIM];
  int t = threadIdx.x;
  for (int j=t; j<EDIM*DIM; j+=256) sWe[j] = b2f(We[j]);
  if (t < DIM) sAtt[t] = b2f(att[t]);
  __syncthreads();
  int lane = t & 63;
  int node = blockIdx.x*4 + (t>>6);
  float we0[EDIM], we1[EDIM];
  #pragma unroll
  for (int k=0;k<EDIM;k++){ we0[k]=sWe[k*DIM + 2*lane]; we1[k]=sWe[k*DIM + 2*lane + 1]; }
  float att0 = sAtt[2*lane], att1 = sAtt[2*lane+1];
  if (node >= NN) return;
  u32 g = ((const u32*)gr)[(size_t)node*64 + lane];
  float gr0 = b2f_lo(g), gr1 = b2f_hi(g);
  const u32* glv = (const u32*)gl;
  const uint4* ep4 = (const uint4*)eperm;
  float ms[4], ds[4], o0[4], o1[4];
  #pragma unroll
  for (int i=0;i<4;i++){ ms[i] = -INFINITY; ds[i]=0.f; o0[i]=0.f; o1[i]=0.f; }
  int beg = offs[node], end = offs[node+1];
  int e = beg;
  for (; e + 4 <= end; e += 4){
    int sidx[4];
    #pragma unroll
    for (int i=0;i<4;i++) sidx[i] = srcs[e+i];
    u32 gx[4];
    #pragma unroll
    for (int i=0;i<4;i++) gx[i] = glv[(size_t)sidx[i]*64 + lane];
    uint4 ea[8];
    #pragma unroll
    for (int i=0;i<4;i++){ ea[2*i] = ep4[(size_t)(e+i)*2]; ea[2*i+1] = ep4[(size_t)(e+i)*2+1]; }
    #pragma unroll
    for (int i=0;i<4;i++){
      float xj0 = b2f_lo(gx[i]), xj1 = b2f_hi(gx[i]);
      float e0 = xj0 + gr0, e1 = xj1 + gr1;
      u32 eu[8] = {ea[2*i].x, ea[2*i].y, ea[2*i].z, ea[2*i].w,
                   ea[2*i+1].x, ea[2*i+1].y, ea[2*i+1].z, ea[2*i+1].w};
      #pragma unroll
      for (int qq=0;qq<8;qq++){
        float a0 = b2f_lo(eu[qq]), a1 = b2f_hi(eu[qq]);
        e0 += a0*we0[2*qq] + a1*we0[2*qq+1];
        e1 += a0*we1[2*qq] + a1*we1[2*qq+1];
      }
      e0 = e0 > 0.f ? e0 : 0.2f*e0;
      e1 = e1 > 0.f ? e1 : 0.2f*e1;
      float part = e0*att0 + e1*att1;
      part += __shfl_xor(part, 1);
      part += __shfl_xor(part, 2);
      part += __shfl_xor(part, 4);
      part += __shfl_xor(part, 8);
      float nm = fmaxf(ms[i], part);
      float sc = __expf(ms[i] - nm);   // -inf -> 0 on first edge
      float pp = __expf(part - nm);
      ds[i] = ds[i]*sc + pp;
      o0[i] = o0[i]*sc + pp*xj0;
      o1[i] = o1[i]*sc + pp*xj1;
      ms[i] = nm;
    }
  }
  for (; e < end; ++e){
    int s = srcs[e];
    u32 gx = glv[(size_t)s*64 + lane];
    uint4 eaL = ep4[(size_t)e*2], eaH = ep4[(size_t)e*2+1];
    float xj0 = b2f_lo(gx), xj1 = b2f_hi(gx);
    float e0 = xj0 + gr0, e1 = xj1 + gr1;
    u32 eu[8] = {eaL.x, eaL.y, eaL.z, eaL.w, eaH.x, eaH.y, eaH.z, eaH.w};
    #pragma unroll
    for (int qq=0;qq<8;qq++){
      float a0 = b2f_lo(eu[qq]), a1 = b2f_hi(eu[qq]);
      e0 += a0*we0[2*qq] + a1*we0[2*qq+1];
      e1 += a0*we1[2*qq] + a1*we1[2*qq+1];
    }
    e0 = e0 > 0.f ? e0 : 0.2f*e0;
    e1 = e1 > 0.f ? e1 : 0.2f*e1;
    float part = e0*att0 + e1*att1;
    part += __shfl_xor(part, 1);
    part += __shfl_xor(part, 2);
    part += __shfl_xor(part, 4);
    part += __shfl_xor(part, 8);
    float nm = fmaxf(ms[0], part);
    float sc = __expf(ms[0] - nm);
    float pp = __expf(part - nm);
    ds[0] = ds[0]*sc + pp;
    o0[0] = o0[0]*sc + pp*xj0;
    o1[0] = o1[0]*sc + pp*xj1;
    ms[0] = nm;
  }
  // merge states (guard -inf: empty state contributes 0)
  float M = fmaxf(fmaxf(ms[0],ms[1]), fmaxf(ms[2],ms[3]));
  float D = 0.f, P0 = 0.f, P1 = 0.f;
  #pragma unroll
  for (int i=0;i<4;i++){
    if (ms[i] != -INFINITY){
      float sc = __expf(ms[i] - M);
      D += sc*ds[i]; P0 += sc*o0[i]; P1 += sc*o1[i];
    }
  }
  float inv = 1.f/(D + 1e-16f);
  ((float2*)agg)[(size_t)node*64 + lane] = make_float2(P0*inv, P1*inv);
}

// ---------------- batch norm ----------------
__global__ __launch_bounds__(256) void k_bnstats(const float* __restrict__ agg, float* __restrict__ stats){
  int t = threadIdx.x;
  int p = t & 63;
  int rg = t >> 6;
  float s0=0,s1=0,q0=0,q1=0;
  for (int r = blockIdx.x*4 + rg; r < NN; r += 256*4){
    float2 v = ((const float2*)agg)[(size_t)r*64 + p];
    s0 += v.x; s1 += v.y; q0 += v.x*v.x; q1 += v.y*v.y;
  }
  int c0 = 2*p;
  atomicAdd(&stats[c0],     s0); atomicAdd(&stats[c0+1],     s1);
  atomicAdd(&stats[DIM+c0], q0); atomicAdd(&stats[DIM+c0+1], q1);
}

__global__ __launch_bounds__(256) void k_bnapply(const float* __restrict__ agg, const float* __restrict__ stats,
    const u16* __restrict__ gamma, const u16* __restrict__ beta, float* __restrict__ h){
  int i = blockIdx.x*256 + threadIdx.x;
  if (i >= NN*64) return;
  int p = i & 63; int c0 = 2*p;
  float2 v = ((const float2*)agg)[i];
  const float invN = 1.f/(float)NN;
  float mu0 = stats[c0]*invN,   mu1 = stats[c0+1]*invN;
  float va0 = stats[DIM+c0]*invN   - mu0*mu0;
  float va1 = stats[DIM+c0+1]*invN - mu1*mu1;
  float rs0 = rsqrtf(fmaxf(va0, 0.f) + 1e-5f), rs1 = rsqrtf(fmaxf(va1, 0.f) + 1e-5f);
  float y0 = (v.x - mu0)*rs0*b2f(gamma[c0])   + b2f(beta[c0]);
  float y1 = (v.y - mu1)*rs1*b2f(gamma[c0+1]) + b2f(beta[c0+1]);
  y0 = y0 > 0.f ? y0 : 0.02f*y0;
  y1 = y1 > 0.f ? y1 : 0.02f*y1;
  ((float2*)h)[i] = make_float2(y0, y1);
}

// ---------------- launch ----------------
extern "C" void kernel_launch(void* const* d_in, const int* in_sizes, int n_in,
                              void* d_out, int out_size, void* d_ws, size_t ws_size,
                              hipStream_t stream){
  (void)in_sizes; (void)n_in; (void)out_size; (void)ws_size;
  const void* x    = d_in[0];
  const int* ei    = (const int*)d_in[1];
  const void* eattr= d_in[2];
  // d_in[9] = conv bias: cancels under BN mean-subtraction, skipped
  char* p = (char*)d_ws;
  auto alloc = [&](size_t b)->void*{ void* q = p; p += (b + 255) & ~(size_t)255; return q; };
  float* h      = (float*)alloc((size_t)NN*DIM*4);    // features; also attn output + BN in-place
  u16*   gl     = (u16*)  alloc((size_t)NN*DIM*2);
  u16*   gr     = (u16*)  alloc((size_t)NN*DIM*2);
  int*   offs   = (int*)  alloc((size_t)(NN+1)*4);
  int*   counts = (int*)  alloc((size_t)NN*4);
  int*   srcs   = (int*)  alloc((size_t)NE*4);
  u16*   eperm  = (u16*)  alloc((size_t)NE*EDIM*2);   // edge_attr in CSR order, bf16
  float* stats  = (float*)alloc(256*4);
  int*   bsums  = (int*)  alloc(128*4);
  int*   flags  = (int*)  alloc(8);                   // [0]=fflag, [1]=iflag
  u16*   cpar   = (u16*)  alloc((size_t)SEG_TOTAL*2);

  int* fflag = flags;
  int* iflag = flags + 1;

  k_zero32<<<1,256,0,stream>>>(flags, 2);
  k_probe_f<<<1,256,0,stream>>>((const u16*)x, fflag);
  k_probe_i<<<4,256,0,stream>>>(ei, iflag);
  k_cvt_params<<<(SEG_TOTAL+255)/256,256,0,stream>>>(d_in[3], d_in[5], d_in[7], d_in[8],
      d_in[10], d_in[11], d_in[12], d_in[13], d_in[4], d_in[6], cpar, fflag);
  const u16* cWlT= cpar + SEG_WL;  const u16* cWrT= cpar + SEG_WR;
  const u16* cWe = cpar + SEG_WE;  const u16* cAtt= cpar + SEG_ATT;
  const u16* cGam= cpar + SEG_GAM; const u16* cBet= cpar + SEG_BET;
  const u16* cWfT= cpar + SEG_WF;  const u16* cBf = cpar + SEG_BF;
  const u16* cBl = cpar + SEG_BL;  const u16* cBr = cpar + SEG_BR;

  k_x2f<<<(NN*DIM/4+255)/256,256,0,stream>>>(x, h, fflag);
  k_zero32<<<(NN+255)/256,256,0,stream>>>(counts, NN);
  k_count<<<(NE+255)/256,256,0,stream>>>(ei, iflag, counts);
  const int nbA = (NN+1023)/1024;
  k_scanA<<<nbA,1024,0,stream>>>(counts, offs, bsums);
  k_scanB<<<1,1,0,stream>>>(bsums, offs, nbA);
  k_scanC<<<(NN+255)/256,256,0,stream>>>(offs, bsums);
  k_zero32<<<(NN+255)/256,256,0,stream>>>(counts, NN);
  k_fill<<<(NE+255)/256,256,0,stream>>>(ei, iflag, offs, counts, srcs, eperm, eattr, fflag);

  for (int L=0; L<NL; ++L){
    k_gemm<<<dim3((NN+63)/64,2),256,0,stream>>>(h,
        cWlT + (size_t)L*DIM*DIM, cBl + L*DIM, gl,
        cWrT + (size_t)L*DIM*DIM, cBr + L*DIM, gr, 0, fflag);
    k_zerof<<<1,256,0,stream>>>(stats, 256);
    // attn writes into h (its input features are dead after the GEMM)
    k_attn<<<(NN+3)/4,256,0,stream>>>(offs, srcs, eperm,
        cWe + (size_t)L*EDIM*DIM, cAtt + L*DIM, gl, gr, h);
    k_bnstats<<<256,256,0,stream>>>(h, stats);
    k_bnapply<<<(NN*64+255)/256,256,0,stream>>>(h, stats, cGam + L*DIM, cBet + L*DIM, h);
  }
  k_gemm<<<dim3((NN+63)/64,1),256,0,stream>>>(h, cWfT, cBf, d_out, cWfT, cBf, d_out, 1, fflag);
}